// Round 5
// baseline (307168.433 us; speedup 1.0000x reference)
//
#include <hip/hip_runtime.h>
#include <math.h>

// Problem constants
#define SS 512
#define BBATCH 64
#define TTOK 512
#define CC 128
#define HHID 512
#define AATT 256
#define TPAD 544        // T + 2*PAD
#define CUML 560        // T + 2*(PAD+CUM_PAD)
#define INV_SQRT2 0.70710678118654752440f

// d_ws layout (float offsets); bars occupy first 2048 floats (8KB, memset 0)
#define OFF_PRE    2048
#define OFF_TMP1   (OFF_PRE   + 16777216)
#define OFF_HX     (OFF_TMP1  + 16777216)   // (S+1,B,H)
#define OFF_OHX    (OFF_HX    + 16809984)   // (S+1,B,H)
#define OFF_CTX    (OFF_OHX   + 16809984)   // (S+1,B,A)
#define OFF_TOKP   (OFF_CTX   + 8404992)    // (B,544,A)
#define OFF_INITF  (OFF_TOKP  + 8912896)    // (B,C)
#define OFF_BEGP   (OFF_INITF + 8192)
#define OFF_ENDP   (OFF_BEGP  + 16384)
#define OFF_CUMG   (OFF_ENDP  + 16384)      // (B,560)
#define OFF_WQT    (OFF_CUMG  + 35840)      // (512,256) transposed attn_Wq
#define WS_TOTAL_FLOATS (OFF_WQT + 131072)  // ~339 MB

// d_out offsets (floats)
#define OUT_FRAMES 0
#define OUT_STOP   4194304
#define OUT_ALIGN  4227072
#define OUT_WS     22052864
#define OUT_TOTAL  22085632

struct P {
  const float *tokens, *target_frames;
  const int   *num_tokens;
  const float *init_W1,*init_b1,*init_W2,*init_b2;
  const float *pre_W1,*pre_b1,*pre_W2,*pre_b2;
  const float *lstm_Wih,*lstm_Whh,*lstm_bih,*lstm_bhh;
  const float *attn_Wq,*attn_bq,*attn_conv_w,*attn_conv_b,*attn_v;
  const float *stop_W1,*stop_b1,*stop_W2,*stop_b2;
  const float *olstm_Wih,*olstm_Whh,*olstm_bih,*olstm_bhh;
  const float *out_W1,*out_b1,*out_W2,*out_b2;
  float *pre, *tmp1, *hX, *ohX, *ctxX, *tokp, *initf, *begp, *endp, *cumg, *wqt;
  int *bars0, *bars1;
  float *out_frames, *out_stop, *out_align, *out_ws;
};

__device__ __forceinline__ float sigm(float x){ return 1.f/(1.f+expf(-x)); }
__device__ __forceinline__ float gelu_f(float x){
  float u = 0.7978845608028654f*(x + 0.044715f*x*x*x);
  return 0.5f*x*(1.f + tanhf(u));
}

// Device-scope (LLC write-through) store for the small cross-WG tensors.
__device__ __forceinline__ void g_store(float* ptr, float v) {
  __hip_atomic_store(ptr, v, __ATOMIC_RELAXED, __HIP_MEMORY_SCOPE_AGENT);
}

// Hierarchical grid barrier over exactly 64 WGs (8 groups of 8).
// No fences: communicated data uses sc1 stores; __syncthreads drains vmcnt
// before arrival, so completion ordering gives visibility. Monotonic counters.
// bars layout (ints): [g*32] group arrivals; [256] root; [288] gen;
// [320+g*32] per-group gen broadcast.
__device__ __forceinline__ void gridbar(int* bars, int target) {
  __syncthreads();
  if (threadIdx.x == 0) {
    int g = blockIdx.x >> 3;
    int t = __hip_atomic_fetch_add(&bars[g*32], 1, __ATOMIC_RELAXED, __HIP_MEMORY_SCOPE_AGENT);
    if (t == target*8 - 1) {             // last arrival of this group of 8
      int r = __hip_atomic_fetch_add(&bars[256], 1, __ATOMIC_RELAXED, __HIP_MEMORY_SCOPE_AGENT);
      if (r == target*8 - 1) {           // last group overall -> flip gen
        __hip_atomic_store(&bars[288], target, __ATOMIC_RELAXED, __HIP_MEMORY_SCOPE_AGENT);
      } else {
        while (__hip_atomic_load(&bars[288], __ATOMIC_RELAXED, __HIP_MEMORY_SCOPE_AGENT) < target)
          __builtin_amdgcn_s_sleep(2);
      }
      __hip_atomic_store(&bars[320 + g*32], target, __ATOMIC_RELAXED, __HIP_MEMORY_SCOPE_AGENT);
    } else {
      while (__hip_atomic_load(&bars[320 + g*32], __ATOMIC_RELAXED, __HIP_MEMORY_SCOPE_AGENT) < target)
        __builtin_amdgcn_s_sleep(2);
    }
  }
  __syncthreads();
}

// ---------------- init network ----------------
__global__ __launch_bounds__(256) void k_init(P p) {
  int b = blockIdx.x; int tid = threadIdx.x;
  __shared__ float fl[512];
  __shared__ float h1[256];
  __shared__ float cumv_s;
  int nt = p.num_tokens[b];
  fl[tid]       = p.tokens[(size_t)b*AATT + tid];                       // tokens[0,b,:]
  fl[256+tid]   = p.tokens[((size_t)(nt-1)*BBATCH + b)*AATT + tid];     // tokens[nt-1,b,:]
  __syncthreads();
  {
    float a1 = p.init_b1[tid];
    for (int k = 0; k < 512; ++k) a1 = fmaf(fl[k], p.init_W1[(size_t)tid*512 + k], a1);
    h1[tid] = gelu_f(a1);
  }
  __syncthreads();
  for (int j = tid; j < 897; j += 256) {
    float a2 = p.init_b2[j];
    for (int k = 0; k < 256; ++k) a2 = fmaf(h1[k], p.init_W2[(size_t)j*256 + k], a2);
    if (j < 128)      p.initf[b*CC + j] = a2;
    else if (j == 128) cumv_s = fabsf(a2);
    else if (j < 385) p.ctxX[(size_t)b*AATT + (j-129)] = a2;   // ctx_histX[0][b]
    else if (j < 641) p.begp[b*AATT + (j-385)] = a2;
    else              p.endp[b*AATT + (j-641)] = a2;
  }
  for (int k = tid; k < 512; k += 256) {
    p.hX[(size_t)b*HHID + k]  = 0.f;   // h_histX[0]
    p.ohX[(size_t)b*HHID + k] = 0.f;   // oh_histX[0]
  }
  __syncthreads();
  float cv = cumv_s;
  for (int i = tid; i < CUML; i += 256) p.cumg[b*CUML + i] = (i < 24) ? cv : 0.f;
}

// ---------------- transpose attn_Wq -> (512,256) ----------------
__global__ __launch_bounds__(256) void k_wqt(P p) {
  int idx = blockIdx.x*256 + threadIdx.x;
  if (idx < 512*256) { int k = idx >> 8, a = idx & 255; p.wqt[idx] = p.attn_Wq[(size_t)a*512 + k]; }
}

// ---------------- build tok_p (B,544,A) ----------------
__global__ __launch_bounds__(256) void k_tokp(P p) {
  int idx = blockIdx.x*256 + threadIdx.x;      // float4 index
  if (idx >= BBATCH*TPAD*(AATT/4)) return;
  int a4 = idx & 63; int pt = idx >> 6; int pos = pt % TPAD; int b = pt / TPAD;
  int nt = p.num_tokens[b];
  float4 v;
  if (pos < 16)             v = *(const float4*)&p.begp[b*AATT + (a4<<2)];
  else if (pos - 16 < nt)   v = *(const float4*)&p.tokens[((size_t)(pos-16)*BBATCH + b)*AATT + (a4<<2)];
  else if (pos < nt + 32)   v = *(const float4*)&p.endp[b*AATT + (a4<<2)];
  else                      v = make_float4(0.f,0.f,0.f,0.f);
  *(float4*)&p.tokp[((size_t)b*TPAD + pos)*AATT + (a4<<2)] = v;
}

// ---------------- generic fp32 GEMM: C(32768 x N) = act(A(32768 x K) @ W^T + bias) ----------------
template<int KD, int ND, int ASRC, int EPI>
__device__ __forceinline__ float4 fetchA(const P& p, int grow, int gk) {
  if (ASRC == 0) return *(const float4*)&p.tmp1[(size_t)grow*512 + gk];
  if (ASRC == 1) {
    if (grow < 64) return *(const float4*)&p.initf[grow*CC + gk];
    return *(const float4*)&p.target_frames[(size_t)(grow-64)*CC + gk];
  }
  if (ASRC == 2) {
    if (gk < 512) {
      float4 a = *(const float4*)&p.pre[(size_t)grow*512 + gk];
      float4 b = *(const float4*)&p.hX[(size_t)(grow+64)*512 + gk];
      return make_float4((a.x+b.x)*INV_SQRT2,(a.y+b.y)*INV_SQRT2,(a.z+b.z)*INV_SQRT2,(a.w+b.w)*INV_SQRT2);
    }
    return *(const float4*)&p.ctxX[(size_t)(grow+64)*256 + (gk-512)];
  }
  { // ASRC 3
    float4 a = *(const float4*)&p.pre[(size_t)grow*512 + gk];
    float4 b = *(const float4*)&p.ohX[(size_t)(grow+64)*512 + gk];
    return make_float4((a.x+b.x)*INV_SQRT2,(a.y+b.y)*INV_SQRT2,(a.z+b.z)*INV_SQRT2,(a.w+b.w)*INV_SQRT2);
  }
}

template<int KD, int ND, int ASRC, int EPI>
__global__ __launch_bounds__(256, 2) void gemm_k(P p, const float* __restrict__ W,
                                                 const float* __restrict__ bias,
                                                 float* __restrict__ Cout) {
  __shared__ float As[16][132];
  __shared__ float Bs[16][132];
  int tid = threadIdx.x;
  int tx = tid & 15, ty = tid >> 4;
  int mbase = blockIdx.y * 128, nbase = blockIdx.x * 128;
  float acc[8][8];
  #pragma unroll
  for (int u=0;u<8;++u) {
    #pragma unroll
    for (int v=0;v<8;++v) acc[u][v]=0.f;
  }

  for (int k0 = 0; k0 < KD; k0 += 16) {
    __syncthreads();
    #pragma unroll
    for (int u = 0; u < 2; ++u) {
      int f4 = tid*2 + u;
      int r  = f4 >> 2;
      int kq = (f4 & 3) << 2;
      float4 v = fetchA<KD,ND,ASRC,EPI>(p, mbase + r, k0 + kq);
      As[kq+0][r]=v.x; As[kq+1][r]=v.y; As[kq+2][r]=v.z; As[kq+3][r]=v.w;
    }
    #pragma unroll
    for (int u = 0; u < 2; ++u) {
      int f4 = tid*2 + u;
      int r  = f4 >> 2; int kq = (f4 & 3) << 2;
      float4 v = *(const float4*)&W[(size_t)(nbase + r)*KD + (k0 + kq)];
      Bs[kq+0][r]=v.x; Bs[kq+1][r]=v.y; Bs[kq+2][r]=v.z; Bs[kq+3][r]=v.w;
    }
    __syncthreads();
    #pragma unroll
    for (int kk = 0; kk < 16; ++kk) {
      float af[8], bf[8];
      *(float4*)&af[0] = *(const float4*)&As[kk][ty*8];
      *(float4*)&af[4] = *(const float4*)&As[kk][ty*8+4];
      *(float4*)&bf[0] = *(const float4*)&Bs[kk][tx*8];
      *(float4*)&bf[4] = *(const float4*)&Bs[kk][tx*8+4];
      #pragma unroll
      for (int u = 0; u < 8; ++u)
        #pragma unroll
        for (int v = 0; v < 8; ++v)
          acc[u][v] = fmaf(af[u], bf[v], acc[u][v]);
    }
  }

  float bcol[8];
  #pragma unroll
  for (int v=0;v<8;++v) bcol[v] = bias[nbase + tx*8 + v];

  if (EPI == 2) {
    float w2v[8];
    #pragma unroll
    for (int v=0;v<8;++v) w2v[v] = p.stop_W2[nbase + tx*8 + v];
    float rowsum[8];
    #pragma unroll
    for (int u=0;u<8;++u) {
      float s = 0.f;
      #pragma unroll
      for (int v=0;v<8;++v) s = fmaf(gelu_f(acc[u][v] + bcol[v]), w2v[v], s);
      rowsum[u] = s;
    }
    __syncthreads();
    float* red = &As[0][0];
    #pragma unroll
    for (int u=0;u<8;++u) red[(ty*8+u)*16 + tx] = rowsum[u];
    __syncthreads();
    if (tid < 128) {
      float s = 0.f;
      #pragma unroll
      for (int x=0;x<16;++x) s += red[tid*16 + x];
      if (blockIdx.x == 0) s += p.stop_b2[0];
      atomicAdd(&Cout[mbase + tid], s);
    }
  } else {
    #pragma unroll
    for (int u=0;u<8;++u) {
      int grow = mbase + ty*8 + u;
      #pragma unroll
      for (int v4=0;v4<2;++v4) {
        float4 o;
        float x0 = acc[u][v4*4+0] + bcol[v4*4+0];
        float x1 = acc[u][v4*4+1] + bcol[v4*4+1];
        float x2 = acc[u][v4*4+2] + bcol[v4*4+2];
        float x3 = acc[u][v4*4+3] + bcol[v4*4+3];
        if (EPI == 1) { x0=gelu_f(x0); x1=gelu_f(x1); x2=gelu_f(x2); x3=gelu_f(x3); }
        o.x=x0; o.y=x1; o.z=x2; o.w=x3;
        *(float4*)&Cout[(size_t)grow*ND + nbase + tx*8 + v4*4] = o;
      }
    }
  }
}

// ---------------- attention LSTM scan (64 persistent WGs x 1024 thr) ----------------
// WG wg owns h-columns [wg*8, wg*8+8) (x4 gates = 32 gate-rows, amortized over
// all 64 batch rows) AND the attention for batch b = wg. Barrier population 64.
__global__ __launch_bounds__(1024, 1) void k_scan(P p) {
  const int wg = blockIdx.x;       // 0..63
  const int tid = threadIdx.x;     // 0..1023
  __shared__ float smem[64*260];   // stage A: xin chunk; stage B: h/q/loc/score/align
  __shared__ float gbuf[2048];     // [row][gate*8 + jq]
  __shared__ float cstate[512];    // [row*8 + jq]
  __shared__ float cum_lds[CUML];
  __shared__ int ws_s, ws_next;

  const int row = tid >> 4;        // 0..63 (batch row in GEMV)
  const int gci = tid & 15;
  const int jq  = gci & 7;         // h-col within this WG's 8
  const int gg2 = gci >> 3;        // thread computes gates gg2 and gg2+2
  const int hc  = (wg << 3) + jq;  // global h-column
  const int gcA = gg2*HHID + hc;
  const int gcB = (gg2+2)*HHID + hc;
  const float bsA = p.lstm_bih[gcA] + p.lstm_bhh[gcA];
  const float bsB = p.lstm_bih[gcB] + p.lstm_bhh[gcB];

  const int b = wg;
  const int nt = p.num_tokens[b];
  float vreg[4]; float cw[17]; float cbias = 0.f, bqreg = 0.f;
  {
    int lane = tid & 63;
    #pragma unroll
    for (int s2=0;s2<4;++s2) vreg[s2] = p.attn_v[s2*64 + lane];
  }
  if (tid >= 256 && tid < 512) {
    int a = tid - 256;
    #pragma unroll
    for (int k=0;k<17;++k) cw[k] = p.attn_conv_w[a*17 + k];
    cbias = p.attn_conv_b[a];
  }
  if (tid < 256) bqreg = p.attn_bq[tid];
  for (int i = tid; i < CUML; i += 1024) cum_lds[i] = p.cumg[b*CUML + i];
  if (tid == 0) { ws_s = 0; ws_next = 0; }
  if (tid < 512) cstate[tid] = 0.f;
  __syncthreads();

  int gen = 0;
  for (int t = 0; t < SS; ++t) {
    // ===== stage A: gates = [pre_t|ctx|h] @ W^T + b; pointwise -> h =====
    float aA0=0.f,aA1=0.f,aA2=0.f,aA3=0.f;
    float aB0=0.f,aB1=0.f,aB2=0.f,aB3=0.f;
    for (int ch = 0; ch < 5; ++ch) {
      __syncthreads();
      const int kb = ch << 8;
      #pragma unroll
      for (int u = 0; u < 4; ++u) {
        int f4 = (u << 10) + tid;
        int r  = f4 >> 6;
        int kq = (f4 & 63) << 2;
        int kg = kb + kq;
        float4 v;
        if (ch < 2)       v = *(const float4*)&p.pre[((size_t)t*BBATCH + r)*HHID + kg];
        else if (ch == 2) v = *(const float4*)&p.ctxX[((size_t)t*BBATCH + r)*AATT + (kg-512)];
        else              v = *(const float4*)&p.hX[((size_t)t*BBATCH + r)*HHID + (kg-768)];
        *(float4*)&smem[r*260 + kq] = v;
      }
      __syncthreads();
      const float* wbA = (ch < 3) ? (p.lstm_Wih + (size_t)gcA*768 + kb)
                                  : (p.lstm_Whh + (size_t)gcA*512 + (kb-768));
      const float* wbB = (ch < 3) ? (p.lstm_Wih + (size_t)gcB*768 + kb)
                                  : (p.lstm_Whh + (size_t)gcB*512 + (kb-768));
      const float* xr = &smem[row*260];
      #pragma unroll 8
      for (int kk = 0; kk < 256; kk += 4) {
        float4 xv = *(const float4*)&xr[kk];
        float4 wA = *(const float4*)&wbA[kk];
        float4 wB = *(const float4*)&wbB[kk];
        aA0 = fmaf(xv.x, wA.x, aA0);
        aA1 = fmaf(xv.y, wA.y, aA1);
        aA2 = fmaf(xv.z, wA.z, aA2);
        aA3 = fmaf(xv.w, wA.w, aA3);
        aB0 = fmaf(xv.x, wB.x, aB0);
        aB1 = fmaf(xv.y, wB.y, aB1);
        aB2 = fmaf(xv.z, wB.z, aB2);
        aB3 = fmaf(xv.w, wB.w, aB3);
      }
    }
    gbuf[row*32 + gg2*8     + jq] = (aA0+aA1)+(aA2+aA3) + bsA;
    gbuf[row*32 + (gg2+2)*8 + jq] = (aB0+aB1)+(aB2+aB3) + bsB;
    __syncthreads();
    if (tid < 512) {
      int r = tid >> 3, j2 = tid & 7;
      float gi = sigm(gbuf[r*32 +  0 + j2]);
      float gf = sigm(gbuf[r*32 +  8 + j2]);
      float gz = tanhf(gbuf[r*32 + 16 + j2]);
      float go = sigm(gbuf[r*32 + 24 + j2]);
      float cp = cstate[tid];
      float cn = fmaf(gf, cp, gi*gz);
      cstate[tid] = cn;
      float hn = go * tanhf(cn);
      g_store(&p.hX[((size_t)(t+1)*BBATCH + r)*HHID + ((wg<<3)+j2)], hn);  // sc1 -> LLC
    }
    gridbar(p.bars0, ++gen);

    // ===== stage B: attention, each WG handles its own batch b = wg =====
    {
      if (tid < 128)
        *(float4*)&smem[tid<<2] = *(const float4*)&p.hX[((size_t)(t+1)*BBATCH + b)*HHID + (tid<<2)];
      __syncthreads();
      const int ws0 = ws_s;
      if (tid < 256) {          // q = h @ Wq^T + bq (4 chains)
        int a = tid;
        float q0 = bqreg, q1 = 0.f, q2 = 0.f, q3 = 0.f;
        for (int k = 0; k < 512; k += 4) {
          float4 hv = *(const float4*)&smem[k];
          q0 = fmaf(hv.x, p.wqt[(size_t)(k+0)*256 + a], q0);
          q1 = fmaf(hv.y, p.wqt[(size_t)(k+1)*256 + a], q1);
          q2 = fmaf(hv.z, p.wqt[(size_t)(k+2)*256 + a], q2);
          q3 = fmaf(hv.w, p.wqt[(size_t)(k+3)*256 + a], q3);
        }
        smem[512 + a] = (q0 + q1) + (q2 + q3);
      } else if (tid < 512) {   // loc conv (valid, no kernel flip)
        int a = tid - 256;
        for (int w = 0; w < 33; ++w) {
          float la = cbias;
          #pragma unroll
          for (int k = 0; k < 17; ++k) la = fmaf(cw[k], cum_lds[ws0 + w + k], la);
          smem[768 + w*256 + a] = la;
        }
      }
      __syncthreads();
      // scores: 16 waves strided over w, lanes over A
      {
        int wv = tid >> 6, lane = tid & 63;
        for (int w = wv; w < 33; w += 16) {
          float sa = 0.f;
          const float* tw = &p.tokp[((size_t)b*TPAD + (ws0 + w))*AATT];
          #pragma unroll
          for (int s2 = 0; s2 < 4; ++s2) {
            int a = (s2<<6) + lane;
            float x = smem[512+a] + tw[a] + smem[768 + w*256 + a];
            sa = fmaf(tanhf(x), vreg[s2], sa);
          }
          #pragma unroll
          for (int off = 32; off > 0; off >>= 1) sa += __shfl_xor(sa, off, 64);
          if (lane == 0) smem[9216 + w] = sa;
        }
      }
      __syncthreads();
      // softmax + argmax + cum update + ws (single wave)
      if (tid < 64) {
        int w = tid;
        float sc = (w < 33) ? smem[9216+w] : -3.0e38f;
        float mv = sc; int mi = (w < 33) ? w : 64;
        #pragma unroll
        for (int off = 32; off > 0; off >>= 1) {
          float ov = __shfl_xor(mv, off, 64);
          int   oi = __shfl_xor(mi, off, 64);
          if (ov > mv || (ov == mv && oi < mi)) { mv = ov; mi = oi; }
        }
        float e = (w < 33) ? expf(sc - mv) : 0.f;
        float se = e;
        #pragma unroll
        for (int off = 32; off > 0; off >>= 1) se += __shfl_xor(se, off, 64);
        float al = e / se;
        if (w < 33) {
          smem[9250 + w] = al;
          p.out_align[((size_t)t*BBATCH + b)*TPAD + ws0 + w] = al;
          cum_lds[ws0 + 8 + w] += al;
        }
        if (tid == 0) {
          int wn = ws0 + mi - 16;
          wn = min(max(wn, 0), nt - 1);
          ws_next = wn;
          p.out_ws[t*BBATCH + b] = (float)wn;
        }
      }
      __syncthreads();
      if (tid < 256) {          // ctx = align @ tok_w
        int a = tid;
        float cx = 0.f;
        const float* tw0 = &p.tokp[((size_t)b*TPAD + ws0)*AATT + a];
        #pragma unroll
        for (int w = 0; w < 33; ++w) cx = fmaf(smem[9250+w], tw0[(size_t)w*AATT], cx);
        g_store(&p.ctxX[((size_t)(t+1)*BBATCH + b)*AATT + a], cx);  // sc1 -> LLC
      }
      __syncthreads();
      if (tid == 0) ws_s = ws_next;
    }
    gridbar(p.bars0, ++gen);
  }
}

// ---------------- output LSTM scan (64 persistent WGs x 1024 thr, 1 bar/step) ----------------
__global__ __launch_bounds__(1024, 1) void k_oscan(P p) {
  const int wg = blockIdx.x;
  const int tid = threadIdx.x;
  __shared__ float smem[64*260];
  __shared__ float gbuf[2048];
  __shared__ float cstate[512];

  const int row = tid >> 4;
  const int gci = tid & 15;
  const int jq  = gci & 7;
  const int gg2 = gci >> 3;
  const int hc  = (wg << 3) + jq;
  const int gcA = gg2*HHID + hc;
  const int gcB = (gg2+2)*HHID + hc;
  const float bsA = p.olstm_bih[gcA] + p.olstm_bhh[gcA];
  const float bsB = p.olstm_bih[gcB] + p.olstm_bhh[gcB];

  if (tid < 512) cstate[tid] = 0.f;
  __syncthreads();

  int gen = 0;
  for (int t = 0; t < SS; ++t) {
    float aA0=0.f,aA1=0.f,aA2=0.f,aA3=0.f;
    float aB0=0.f,aB1=0.f,aB2=0.f,aB3=0.f;
    for (int ch = 0; ch < 5; ++ch) {
      __syncthreads();
      const int kb = ch << 8;
      #pragma unroll
      for (int u = 0; u < 4; ++u) {
        int f4 = (u << 10) + tid;
        int r  = f4 >> 6;
        int kq = (f4 & 63) << 2;
        int kg = kb + kq;
        float4 v;
        if (ch < 2) {
          float4 a = *(const float4*)&p.pre[((size_t)t*BBATCH + r)*HHID + kg];
          float4 h = *(const float4*)&p.hX[((size_t)(t+1)*BBATCH + r)*HHID + kg];
          v = make_float4((a.x+h.x)*INV_SQRT2,(a.y+h.y)*INV_SQRT2,(a.z+h.z)*INV_SQRT2,(a.w+h.w)*INV_SQRT2);
        }
        else if (ch == 2) v = *(const float4*)&p.ctxX[((size_t)(t+1)*BBATCH + r)*AATT + (kg-512)];
        else              v = *(const float4*)&p.ohX[((size_t)t*BBATCH + r)*HHID + (kg-768)];
        *(float4*)&smem[r*260 + kq] = v;
      }
      __syncthreads();
      const float* wbA = (ch < 3) ? (p.olstm_Wih + (size_t)gcA*768 + kb)
                                  : (p.olstm_Whh + (size_t)gcA*512 + (kb-768));
      const float* wbB = (ch < 3) ? (p.olstm_Wih + (size_t)gcB*768 + kb)
                                  : (p.olstm_Whh + (size_t)gcB*512 + (kb-768));
      const float* xr = &smem[row*260];
      #pragma unroll 8
      for (int kk = 0; kk < 256; kk += 4) {
        float4 xv = *(const float4*)&xr[kk];
        float4 wA = *(const float4*)&wbA[kk];
        float4 wB = *(const float4*)&wbB[kk];
        aA0 = fmaf(xv.x, wA.x, aA0);
        aA1 = fmaf(xv.y, wA.y, aA1);
        aA2 = fmaf(xv.z, wA.z, aA2);
        aA3 = fmaf(xv.w, wA.w, aA3);
        aB0 = fmaf(xv.x, wB.x, aB0);
        aB1 = fmaf(xv.y, wB.y, aB1);
        aB2 = fmaf(xv.z, wB.z, aB2);
        aB3 = fmaf(xv.w, wB.w, aB3);
      }
    }
    gbuf[row*32 + gg2*8     + jq] = (aA0+aA1)+(aA2+aA3) + bsA;
    gbuf[row*32 + (gg2+2)*8 + jq] = (aB0+aB1)+(aB2+aB3) + bsB;
    __syncthreads();
    if (tid < 512) {
      int r = tid >> 3, j2 = tid & 7;
      float gi = sigm(gbuf[r*32 +  0 + j2]);
      float gf = sigm(gbuf[r*32 +  8 + j2]);
      float gz = tanhf(gbuf[r*32 + 16 + j2]);
      float go = sigm(gbuf[r*32 + 24 + j2]);
      float cp = cstate[tid];
      float cn = fmaf(gf, cp, gi*gz);
      cstate[tid] = cn;
      float hn = go * tanhf(cn);
      g_store(&p.ohX[((size_t)(t+1)*BBATCH + r)*HHID + ((wg<<3)+j2)], hn);  // sc1 -> LLC
    }
    gridbar(p.bars1, ++gen);
  }
}

__global__ void k_sentinel(float* o) { o[blockIdx.x*256 + threadIdx.x] = 12345.0f; }

extern "C" void kernel_launch(void* const* d_in, const int* in_sizes, int n_in,
                              void* d_out, int out_size, void* d_ws, size_t ws_size,
                              hipStream_t stream) {
  P p;
  p.tokens        = (const float*)d_in[0];
  p.num_tokens    = (const int*)d_in[2];
  p.target_frames = (const float*)d_in[3];
  p.init_W1=(const float*)d_in[4];  p.init_b1=(const float*)d_in[5];
  p.init_W2=(const float*)d_in[6];  p.init_b2=(const float*)d_in[7];
  p.pre_W1=(const float*)d_in[8];   p.pre_b1=(const float*)d_in[9];
  p.pre_W2=(const float*)d_in[10];  p.pre_b2=(const float*)d_in[11];
  p.lstm_Wih=(const float*)d_in[12]; p.lstm_Whh=(const float*)d_in[13];
  p.lstm_bih=(const float*)d_in[14]; p.lstm_bhh=(const float*)d_in[15];
  p.attn_Wq=(const float*)d_in[16]; p.attn_bq=(const float*)d_in[17];
  p.attn_conv_w=(const float*)d_in[18]; p.attn_conv_b=(const float*)d_in[19];
  p.attn_v=(const float*)d_in[20];
  p.stop_W1=(const float*)d_in[21]; p.stop_b1=(const float*)d_in[22];
  p.stop_W2=(const float*)d_in[23]; p.stop_b2=(const float*)d_in[24];
  p.olstm_Wih=(const float*)d_in[25]; p.olstm_Whh=(const float*)d_in[26];
  p.olstm_bih=(const float*)d_in[27]; p.olstm_bhh=(const float*)d_in[28];
  p.out_W1=(const float*)d_in[29];  p.out_b1=(const float*)d_in[30];
  p.out_W2=(const float*)d_in[31];  p.out_b2=(const float*)d_in[32];

  float* w = (float*)d_ws;
  p.bars0 = (int*)d_ws;          // ints [0..575]
  p.bars1 = p.bars0 + 1024;      // ints [1024..1599]
  p.pre   = w + OFF_PRE;
  p.tmp1  = w + OFF_TMP1;
  p.hX    = w + OFF_HX;
  p.ohX   = w + OFF_OHX;
  p.ctxX  = w + OFF_CTX;
  p.tokp  = w + OFF_TOKP;
  p.initf = w + OFF_INITF;
  p.begp  = w + OFF_BEGP;
  p.endp  = w + OFF_ENDP;
  p.cumg  = w + OFF_CUMG;
  p.wqt   = w + OFF_WQT;

  p.out_frames = (float*)d_out;
  p.out_stop   = p.out_frames + OUT_STOP;
  p.out_align  = p.out_frames + OUT_ALIGN;
  p.out_ws     = p.out_frames + OUT_WS;

  (void)hipMemsetAsync(d_out, 0, (size_t)out_size * sizeof(float), stream);

  if (ws_size < (size_t)WS_TOTAL_FLOATS * sizeof(float)) {
    k_sentinel<<<128, 256, 0, stream>>>(p.out_ws);
    return;
  }

  (void)hipMemsetAsync(d_ws, 0, 8192, stream);     // barrier counters (both scans)

  k_init<<<64, 256, 0, stream>>>(p);
  k_wqt <<<512, 256, 0, stream>>>(p);
  k_tokp<<<8704, 256, 0, stream>>>(p);

  // pre = gelu(gelu(frames_in @ pre_W1^T + b1) @ pre_W2^T + b2)
  gemm_k<128,512,1,1><<<dim3(4,256), 256, 0, stream>>>(p, p.pre_W1, p.pre_b1, p.tmp1);
  gemm_k<512,512,0,1><<<dim3(4,256), 256, 0, stream>>>(p, p.pre_W2, p.pre_b2, p.pre);

  k_scan<<<64, 1024, 0, stream>>>(p);

  // stop = gelu(block @ stop_W1^T + b1) @ stop_W2^T + b2   (fused reduce)
  gemm_k<768,512,2,2><<<dim3(4,256), 256, 0, stream>>>(p, p.stop_W1, p.stop_b1, p.out_stop);

  k_oscan<<<64, 1024, 0, stream>>>(p);

  // frames = gelu(fr2 @ out_W1^T + b1) @ out_W2^T + b2
  gemm_k<512,512,3,1><<<dim3(4,256), 256, 0, stream>>>(p, p.out_W1, p.out_b1, p.tmp1);
  gemm_k<512,128,0,0><<<dim3(1,256), 256, 0, stream>>>(p, p.out_W2, p.out_b2, p.out_frames);
}

// Round 7
// 59416.547 us; speedup vs baseline: 5.1697x; 5.1697x over previous
//
#include <hip/hip_runtime.h>
#include <math.h>

// Problem constants
#define SS 512
#define BBATCH 64
#define TTOK 512
#define CC 128
#define HHID 512
#define AATT 256
#define TPAD 544        // T + 2*PAD
#define CUML 560        // T + 2*(PAD+CUM_PAD)
#define NWG 256
#define INV_SQRT2 0.70710678118654752440f

// d_ws layout (float offsets); bars occupy first 2048 floats (8KB, memset 0)
#define OFF_PRE    2048
#define OFF_TMP1   (OFF_PRE   + 16777216)
#define OFF_HX     (OFF_TMP1  + 16777216)   // (S+1,B,H)
#define OFF_OHX    (OFF_HX    + 16809984)   // (S+1,B,H)
#define OFF_CTX    (OFF_OHX   + 16809984)   // (S+1,B,A)
#define OFF_TOKP   (OFF_CTX   + 8404992)    // (B,544,A)
#define OFF_INITF  (OFF_TOKP  + 8912896)    // (B,C)
#define OFF_BEGP   (OFF_INITF + 8192)
#define OFF_ENDP   (OFF_BEGP  + 16384)
#define OFF_CUMG   (OFF_ENDP  + 16384)      // (B,560)
#define OFF_WQT    (OFF_CUMG  + 35840)      // (512,256) transposed attn_Wq
#define WS_TOTAL_FLOATS (OFF_WQT + 131072)  // ~339 MB

// packed weights live inside the tmp1 region (free between pre-net GEMMs and out-net GEMMs)
#define WP_PER_WG  10240                    // 320 k4 * 8 gci * 4 = 40KB/WG
#define WPO_OFF    4194304                  // olstm pack at tmp1 + 4M floats

// d_out offsets (floats)
#define OUT_FRAMES 0
#define OUT_STOP   4194304
#define OUT_ALIGN  4227072
#define OUT_WS     22052864
#define OUT_TOTAL  22085632

struct P {
  const float *tokens, *target_frames;
  const int   *num_tokens;
  const float *init_W1,*init_b1,*init_W2,*init_b2;
  const float *pre_W1,*pre_b1,*pre_W2,*pre_b2;
  const float *lstm_Wih,*lstm_Whh,*lstm_bih,*lstm_bhh;
  const float *attn_Wq,*attn_bq,*attn_conv_w,*attn_conv_b,*attn_v;
  const float *stop_W1,*stop_b1,*stop_W2,*stop_b2;
  const float *olstm_Wih,*olstm_Whh,*olstm_bih,*olstm_bhh;
  const float *out_W1,*out_b1,*out_W2,*out_b2;
  float *pre, *tmp1, *hX, *ohX, *ctxX, *tokp, *initf, *begp, *endp, *cumg, *wqt;
  float *wpL, *wpO;    // packed lstm/olstm weights: [wg][k4 0..320)[gci 0..8)[4]
  int *bars0, *bars1;
  float *out_frames, *out_stop, *out_align, *out_ws;
};

__device__ __forceinline__ float sigm(float x){ return 1.f/(1.f+expf(-x)); }
__device__ __forceinline__ float gelu_f(float x){
  float u = 0.7978845608028654f*(x + 0.044715f*x*x*x);
  return 0.5f*x*(1.f + tanhf(u));
}

// Device-scope (LLC write-through) store for the small cross-WG tensors.
__device__ __forceinline__ void g_store(float* ptr, float v) {
  __hip_atomic_store(ptr, v, __ATOMIC_RELAXED, __HIP_MEMORY_SCOPE_AGENT);
}

// Hierarchical grid barrier over exactly 256 WGs (8 groups of 32).
// No fences: communicated data uses sc1 stores; __syncthreads drains vmcnt
// before arrival so completion ordering gives visibility. Monotonic counters.
__device__ __forceinline__ void gridbar(int* bars, int target) {
  __syncthreads();
  if (threadIdx.x == 0) {
    int g = blockIdx.x >> 5;
    int t = __hip_atomic_fetch_add(&bars[g*32], 1, __ATOMIC_RELAXED, __HIP_MEMORY_SCOPE_AGENT);
    if (t == target*32 - 1) {            // last arrival of this group of 32
      int r = __hip_atomic_fetch_add(&bars[256], 1, __ATOMIC_RELAXED, __HIP_MEMORY_SCOPE_AGENT);
      if (r == target*8 - 1) {           // last group overall -> flip gen
        __hip_atomic_store(&bars[288], target, __ATOMIC_RELAXED, __HIP_MEMORY_SCOPE_AGENT);
      } else {
        while (__hip_atomic_load(&bars[288], __ATOMIC_RELAXED, __HIP_MEMORY_SCOPE_AGENT) < target)
          __builtin_amdgcn_s_sleep(2);
      }
      __hip_atomic_store(&bars[320 + g*32], target, __ATOMIC_RELAXED, __HIP_MEMORY_SCOPE_AGENT);
    } else {
      while (__hip_atomic_load(&bars[320 + g*32], __ATOMIC_RELAXED, __HIP_MEMORY_SCOPE_AGENT) < target)
        __builtin_amdgcn_s_sleep(2);
    }
  }
  __syncthreads();
}

// ---------------- init network ----------------
__global__ __launch_bounds__(256) void k_init(P p) {
  int b = blockIdx.x; int tid = threadIdx.x;
  __shared__ float fl[512];
  __shared__ float h1[256];
  __shared__ float cumv_s;
  int nt = p.num_tokens[b];
  fl[tid]       = p.tokens[(size_t)b*AATT + tid];                       // tokens[0,b,:]
  fl[256+tid]   = p.tokens[((size_t)(nt-1)*BBATCH + b)*AATT + tid];     // tokens[nt-1,b,:]
  __syncthreads();
  {
    float a1 = p.init_b1[tid];
    for (int k = 0; k < 512; ++k) a1 = fmaf(fl[k], p.init_W1[(size_t)tid*512 + k], a1);
    h1[tid] = gelu_f(a1);
  }
  __syncthreads();
  for (int j = tid; j < 897; j += 256) {
    float a2 = p.init_b2[j];
    for (int k = 0; k < 256; ++k) a2 = fmaf(h1[k], p.init_W2[(size_t)j*256 + k], a2);
    if (j < 128)      p.initf[b*CC + j] = a2;
    else if (j == 128) cumv_s = fabsf(a2);
    else if (j < 385) p.ctxX[(size_t)b*AATT + (j-129)] = a2;   // ctx_histX[0][b]
    else if (j < 641) p.begp[b*AATT + (j-385)] = a2;
    else              p.endp[b*AATT + (j-641)] = a2;
  }
  for (int k = tid; k < 512; k += 256) {
    p.hX[(size_t)b*HHID + k]  = 0.f;   // h_histX[0]
    p.ohX[(size_t)b*HHID + k] = 0.f;   // oh_histX[0]
  }
  __syncthreads();
  float cv = cumv_s;
  for (int i = tid; i < CUML; i += 256) p.cumg[b*CUML + i] = (i < 24) ? cv : 0.f;
}

// ---------------- transpose attn_Wq -> (512,256) ----------------
__global__ __launch_bounds__(256) void k_wqt(P p) {
  int idx = blockIdx.x*256 + threadIdx.x;
  if (idx < 512*256) { int k = idx >> 8, a = idx & 255; p.wqt[idx] = p.attn_Wq[(size_t)a*512 + k]; }
}

// ---------------- build tok_p (B,544,A) ----------------
__global__ __launch_bounds__(256) void k_tokp(P p) {
  int idx = blockIdx.x*256 + threadIdx.x;      // float4 index
  if (idx >= BBATCH*TPAD*(AATT/4)) return;
  int a4 = idx & 63; int pt = idx >> 6; int pos = pt % TPAD; int b = pt / TPAD;
  int nt = p.num_tokens[b];
  float4 v;
  if (pos < 16)             v = *(const float4*)&p.begp[b*AATT + (a4<<2)];
  else if (pos - 16 < nt)   v = *(const float4*)&p.tokens[((size_t)(pos-16)*BBATCH + b)*AATT + (a4<<2)];
  else if (pos < nt + 32)   v = *(const float4*)&p.endp[b*AATT + (a4<<2)];
  else                      v = make_float4(0.f,0.f,0.f,0.f);
  *(float4*)&p.tokp[((size_t)b*TPAD + pos)*AATT + (a4<<2)] = v;
}

// ---------------- pack LSTM weights per-WG interleaved-by-gatecol ----------------
// wp[wg][k4][gci][c] = W[gatecol(wg,gci)][k4*4+c]; gatecol = (gci>>1)*512 + 2*wg + (gci&1)
// k<768 from Wih (row length 768), k>=768 from Whh (row length 512).
// Result: the 8 gate-rows' same-k float4s are 128B-contiguous -> 2-line weight
// wave-instructions + sequential 40KB stream per WG (was an 8-line gather).
__global__ __launch_bounds__(256) void k_pack(P p) {
  int idx = blockIdx.x*256 + threadIdx.x;      // 0 .. 2*NWG*WP_PER_WG
  int net = 0;
  if (idx >= NWG*WP_PER_WG) { net = 1; idx -= NWG*WP_PER_WG; }
  if (idx >= NWG*WP_PER_WG) return;
  int wg  = idx / WP_PER_WG;                   // 0..255
  int rem = idx - wg*WP_PER_WG;                // (k4<<5) + (gci<<2) + c
  int k4  = rem >> 5;                          // 0..319
  int gci = (rem >> 2) & 7;
  int c   = rem & 3;
  int gatecol = (gci >> 1)*512 + (wg << 1) + (gci & 1);
  int k = k4*4 + c;
  const float* Wih = net ? p.olstm_Wih : p.lstm_Wih;
  const float* Whh = net ? p.olstm_Whh : p.lstm_Whh;
  float v = (k < 768) ? Wih[(size_t)gatecol*768 + k] : Whh[(size_t)gatecol*512 + (k - 768)];
  float* dst = net ? p.wpO : p.wpL;
  dst[(size_t)wg*WP_PER_WG + rem] = v;
}

// ---------------- generic fp32 GEMM: C(32768 x N) = act(A(32768 x K) @ W^T + bias) ----------------
template<int KD, int ND, int ASRC, int EPI>
__device__ __forceinline__ float4 fetchA(const P& p, int grow, int gk) {
  if (ASRC == 0) return *(const float4*)&p.tmp1[(size_t)grow*512 + gk];
  if (ASRC == 1) {
    if (grow < 64) return *(const float4*)&p.initf[grow*CC + gk];
    return *(const float4*)&p.target_frames[(size_t)(grow-64)*CC + gk];
  }
  if (ASRC == 2) {
    if (gk < 512) {
      float4 a = *(const float4*)&p.pre[(size_t)grow*512 + gk];
      float4 b = *(const float4*)&p.hX[(size_t)(grow+64)*512 + gk];
      return make_float4((a.x+b.x)*INV_SQRT2,(a.y+b.y)*INV_SQRT2,(a.z+b.z)*INV_SQRT2,(a.w+b.w)*INV_SQRT2);
    }
    return *(const float4*)&p.ctxX[(size_t)(grow+64)*256 + (gk-512)];
  }
  { // ASRC 3
    float4 a = *(const float4*)&p.pre[(size_t)grow*512 + gk];
    float4 b = *(const float4*)&p.ohX[(size_t)(grow+64)*512 + gk];
    return make_float4((a.x+b.x)*INV_SQRT2,(a.y+b.y)*INV_SQRT2,(a.z+b.z)*INV_SQRT2,(a.w+b.w)*INV_SQRT2);
  }
}

template<int KD, int ND, int ASRC, int EPI>
__global__ __launch_bounds__(256, 2) void gemm_k(P p, const float* __restrict__ W,
                                                 const float* __restrict__ bias,
                                                 float* __restrict__ Cout) {
  __shared__ float As[16][132];
  __shared__ float Bs[16][132];
  int tid = threadIdx.x;
  int tx = tid & 15, ty = tid >> 4;
  int mbase = blockIdx.y * 128, nbase = blockIdx.x * 128;
  float acc[8][8];
  #pragma unroll
  for (int u=0;u<8;++u) {
    #pragma unroll
    for (int v=0;v<8;++v) acc[u][v]=0.f;
  }

  for (int k0 = 0; k0 < KD; k0 += 16) {
    __syncthreads();
    #pragma unroll
    for (int u = 0; u < 2; ++u) {
      int f4 = tid*2 + u;
      int r  = f4 >> 2;
      int kq = (f4 & 3) << 2;
      float4 v = fetchA<KD,ND,ASRC,EPI>(p, mbase + r, k0 + kq);
      As[kq+0][r]=v.x; As[kq+1][r]=v.y; As[kq+2][r]=v.z; As[kq+3][r]=v.w;
    }
    #pragma unroll
    for (int u = 0; u < 2; ++u) {
      int f4 = tid*2 + u;
      int r  = f4 >> 2; int kq = (f4 & 3) << 2;
      float4 v = *(const float4*)&W[(size_t)(nbase + r)*KD + (k0 + kq)];
      Bs[kq+0][r]=v.x; Bs[kq+1][r]=v.y; Bs[kq+2][r]=v.z; Bs[kq+3][r]=v.w;
    }
    __syncthreads();
    #pragma unroll
    for (int kk = 0; kk < 16; ++kk) {
      float af[8], bf[8];
      *(float4*)&af[0] = *(const float4*)&As[kk][ty*8];
      *(float4*)&af[4] = *(const float4*)&As[kk][ty*8+4];
      *(float4*)&bf[0] = *(const float4*)&Bs[kk][tx*8];
      *(float4*)&bf[4] = *(const float4*)&Bs[kk][tx*8+4];
      #pragma unroll
      for (int u = 0; u < 8; ++u)
        #pragma unroll
        for (int v = 0; v < 8; ++v)
          acc[u][v] = fmaf(af[u], bf[v], acc[u][v]);
    }
  }

  float bcol[8];
  #pragma unroll
  for (int v=0;v<8;++v) bcol[v] = bias[nbase + tx*8 + v];

  if (EPI == 2) {
    float w2v[8];
    #pragma unroll
    for (int v=0;v<8;++v) w2v[v] = p.stop_W2[nbase + tx*8 + v];
    float rowsum[8];
    #pragma unroll
    for (int u=0;u<8;++u) {
      float s = 0.f;
      #pragma unroll
      for (int v=0;v<8;++v) s = fmaf(gelu_f(acc[u][v] + bcol[v]), w2v[v], s);
      rowsum[u] = s;
    }
    __syncthreads();
    float* red = &As[0][0];
    #pragma unroll
    for (int u=0;u<8;++u) red[(ty*8+u)*16 + tx] = rowsum[u];
    __syncthreads();
    if (tid < 128) {
      float s = 0.f;
      #pragma unroll
      for (int x=0;x<16;++x) s += red[tid*16 + x];
      if (blockIdx.x == 0) s += p.stop_b2[0];
      atomicAdd(&Cout[mbase + tid], s);
    }
  } else {
    #pragma unroll
    for (int u=0;u<8;++u) {
      int grow = mbase + ty*8 + u;
      #pragma unroll
      for (int v4=0;v4<2;++v4) {
        float4 o;
        float x0 = acc[u][v4*4+0] + bcol[v4*4+0];
        float x1 = acc[u][v4*4+1] + bcol[v4*4+1];
        float x2 = acc[u][v4*4+2] + bcol[v4*4+2];
        float x3 = acc[u][v4*4+3] + bcol[v4*4+3];
        if (EPI == 1) { x0=gelu_f(x0); x1=gelu_f(x1); x2=gelu_f(x2); x3=gelu_f(x3); }
        o.x=x0; o.y=x1; o.z=x2; o.w=x3;
        *(float4*)&Cout[(size_t)grow*ND + nbase + tx*8 + v4*4] = o;
      }
    }
  }
}

// ---------------- attention LSTM scan (persistent, 256 WGs x 512 thr) ----------------
__global__ __launch_bounds__(512, 1) void k_scan(P p) {
  const int wg = blockIdx.x;
  const int tid = threadIdx.x;
  __shared__ float smem[64*260];     // stage A: xin chunk; stage B: h/q/loc/score/align
  __shared__ float gbuf[512];
  __shared__ float cstate[128];
  __shared__ float cum_lds[CUML];
  __shared__ int ws_s, ws_next;

  const int row = tid >> 3;
  const int gci = tid & 7;
  const int jq0 = gci & 1, gg = gci >> 1;
  const int jcol = (wg<<1) + jq0;
  const int gatecol = gg*HHID + jcol;
  const float bsum = p.lstm_bih[gatecol] + p.lstm_bhh[gatecol];
  const float* wpw = p.wpL + (size_t)wg*WP_PER_WG;   // packed 40KB stream
  const int gsh = gci << 2;

  const int b = wg;
  int nt = 0; float vreg[4]; float cw[17]; float cbias = 0.f, bqreg = 0.f;
  if (wg < 64) {
    nt = p.num_tokens[b];
    int lane = tid & 63;
    #pragma unroll
    for (int s2=0;s2<4;++s2) vreg[s2] = p.attn_v[s2*64 + lane];
    if (tid >= 256) {
      int a = tid - 256;
      #pragma unroll
      for (int k=0;k<17;++k) cw[k] = p.attn_conv_w[a*17 + k];
      cbias = p.attn_conv_b[a];
    }
    if (tid < 256) bqreg = p.attn_bq[tid];
    for (int i = tid; i < CUML; i += 512) cum_lds[i] = p.cumg[b*CUML + i];
    if (tid == 0) { ws_s = 0; ws_next = 0; }
  }
  if (tid < 128) cstate[tid] = 0.f;
  __syncthreads();

  int gen = 0;
  for (int t = 0; t < SS; ++t) {
    // ===== stage A: gates = [pre_t|ctx|h] @ W^T + b; pointwise -> h =====
    float a0 = 0.f, a1 = 0.f, a2 = 0.f, a3 = 0.f;   // 4 independent chains
    for (int ch = 0; ch < 5; ++ch) {
      __syncthreads();
      const int kb = ch << 8;
      #pragma unroll
      for (int u = 0; u < 8; ++u) {
        int f4 = (u << 9) + tid;
        int r  = f4 >> 6;
        int kq = (f4 & 63) << 2;
        int kg = kb + kq;
        float4 v;
        if (ch < 2)       v = *(const float4*)&p.pre[((size_t)t*BBATCH + r)*HHID + kg];
        else if (ch == 2) v = *(const float4*)&p.ctxX[((size_t)t*BBATCH + r)*AATT + (kg-512)];
        else              v = *(const float4*)&p.hX[((size_t)t*BBATCH + r)*HHID + (kg-768)];
        *(float4*)&smem[r*260 + kq] = v;
      }
      __syncthreads();
      const float* wch = wpw + (ch << 11);   // ch*64*32
      const float* xr = &smem[row*260];
      #pragma unroll 16
      for (int i = 0; i < 64; ++i) {
        float4 xv = *(const float4*)&xr[i<<2];
        float4 wv = *(const float4*)&wch[(i<<5) + gsh];
        a0 = fmaf(xv.x, wv.x, a0);
        a1 = fmaf(xv.y, wv.y, a1);
        a2 = fmaf(xv.z, wv.z, a2);
        a3 = fmaf(xv.w, wv.w, a3);
      }
    }
    gbuf[(row<<3) + gci] = (a0 + a1) + (a2 + a3) + bsum;
    __syncthreads();
    if (tid < 128) {
      int r = tid >> 1, jq = tid & 1;
      float gi = sigm(gbuf[(r<<3) + 0 + jq]);
      float gf = sigm(gbuf[(r<<3) + 2 + jq]);
      float gz = tanhf(gbuf[(r<<3) + 4 + jq]);
      float go = sigm(gbuf[(r<<3) + 6 + jq]);
      float cp = cstate[(r<<1)+jq];
      float cn = fmaf(gf, cp, gi*gz);
      cstate[(r<<1)+jq] = cn;
      float hn = go * tanhf(cn);
      g_store(&p.hX[((size_t)(t+1)*BBATCH + r)*HHID + ((wg<<1)+jq)], hn);  // sc1 -> LLC
    }
    gridbar(p.bars0, ++gen);

    // ===== stage B: attention (WGs 0..63, one per batch row) =====
    if (wg < 64) {
      if (tid < 128)
        *(float4*)&smem[tid<<2] = *(const float4*)&p.hX[((size_t)(t+1)*BBATCH + b)*HHID + (tid<<2)];
      __syncthreads();
      const int ws0 = ws_s;
      if (tid < 256) {          // q = h @ Wq^T + bq (4 chains)
        int a = tid;
        float q0 = bqreg, q1 = 0.f, q2 = 0.f, q3 = 0.f;
        for (int k = 0; k < 512; k += 4) {
          float4 hv = *(const float4*)&smem[k];
          q0 = fmaf(hv.x, p.wqt[(size_t)(k+0)*256 + a], q0);
          q1 = fmaf(hv.y, p.wqt[(size_t)(k+1)*256 + a], q1);
          q2 = fmaf(hv.z, p.wqt[(size_t)(k+2)*256 + a], q2);
          q3 = fmaf(hv.w, p.wqt[(size_t)(k+3)*256 + a], q3);
        }
        smem[512 + a] = (q0 + q1) + (q2 + q3);
      } else {                  // loc conv (valid, no kernel flip)
        int a = tid - 256;
        for (int w = 0; w < 33; ++w) {
          float la = cbias;
          #pragma unroll
          for (int k = 0; k < 17; ++k) la = fmaf(cw[k], cum_lds[ws0 + w + k], la);
          smem[768 + w*256 + a] = la;
        }
      }
      __syncthreads();
      // scores: wave per w (strided), lanes over A
      {
        int wv = tid >> 6, lane = tid & 63;
        for (int w = wv; w < 33; w += 8) {
          float sa = 0.f;
          const float* tw = &p.tokp[((size_t)b*TPAD + (ws0 + w))*AATT];
          #pragma unroll
          for (int s2 = 0; s2 < 4; ++s2) {
            int a = (s2<<6) + lane;
            float x = smem[512+a] + tw[a] + smem[768 + w*256 + a];
            sa = fmaf(tanhf(x), vreg[s2], sa);
          }
          #pragma unroll
          for (int off = 32; off > 0; off >>= 1) sa += __shfl_xor(sa, off, 64);
          if (lane == 0) smem[9216 + w] = sa;
        }
      }
      __syncthreads();
      // softmax + argmax + cum update + ws (single wave)
      if (tid < 64) {
        int w = tid;
        float sc = (w < 33) ? smem[9216+w] : -3.0e38f;
        float mv = sc; int mi = (w < 33) ? w : 64;
        #pragma unroll
        for (int off = 32; off > 0; off >>= 1) {
          float ov = __shfl_xor(mv, off, 64);
          int   oi = __shfl_xor(mi, off, 64);
          if (ov > mv || (ov == mv && oi < mi)) { mv = ov; mi = oi; }
        }
        float e = (w < 33) ? expf(sc - mv) : 0.f;
        float se = e;
        #pragma unroll
        for (int off = 32; off > 0; off >>= 1) se += __shfl_xor(se, off, 64);
        float al = e / se;
        if (w < 33) {
          smem[9250 + w] = al;
          p.out_align[((size_t)t*BBATCH + b)*TPAD + ws0 + w] = al;
          cum_lds[ws0 + 8 + w] += al;
        }
        if (tid == 0) {
          int wn = ws0 + mi - 16;
          wn = min(max(wn, 0), nt - 1);
          ws_next = wn;
          p.out_ws[t*BBATCH + b] = (float)wn;
        }
      }
      __syncthreads();
      if (tid < 256) {          // ctx = align @ tok_w
        int a = tid;
        float cx = 0.f;
        const float* tw0 = &p.tokp[((size_t)b*TPAD + ws0)*AATT + a];
        #pragma unroll
        for (int w = 0; w < 33; ++w) cx = fmaf(smem[9250+w], tw0[(size_t)w*AATT], cx);
        g_store(&p.ctxX[((size_t)(t+1)*BBATCH + b)*AATT + a], cx);  // sc1 -> LLC
      }
      __syncthreads();
      if (tid == 0) ws_s = ws_next;
    }
    gridbar(p.bars0, ++gen);
  }
}

// ---------------- output LSTM scan (persistent) ----------------
__global__ __launch_bounds__(512, 1) void k_oscan(P p) {
  const int wg = blockIdx.x;
  const int tid = threadIdx.x;
  __shared__ float smem[64*260];
  __shared__ float gbuf[512];
  __shared__ float cstate[128];

  const int row = tid >> 3;
  const int gci = tid & 7;
  const int jq0 = gci & 1, gg = gci >> 1;
  const int jcol = (wg<<1) + jq0;
  const int gatecol = gg*HHID + jcol;
  const float bsum = p.olstm_bih[gatecol] + p.olstm_bhh[gatecol];
  const float* wpw = p.wpO + (size_t)wg*WP_PER_WG;
  const int gsh = gci << 2;

  if (tid < 128) cstate[tid] = 0.f;
  __syncthreads();

  int gen = 0;
  for (int t = 0; t < SS; ++t) {
    float a0 = 0.f, a1 = 0.f, a2 = 0.f, a3 = 0.f;
    for (int ch = 0; ch < 5; ++ch) {
      __syncthreads();
      const int kb = ch << 8;
      #pragma unroll
      for (int u = 0; u < 8; ++u) {
        int f4 = (u << 9) + tid;
        int r  = f4 >> 6;
        int kq = (f4 & 63) << 2;
        int kg = kb + kq;
        float4 v;
        if (ch < 2) {
          float4 a = *(const float4*)&p.pre[((size_t)t*BBATCH + r)*HHID + kg];
          float4 h = *(const float4*)&p.hX[((size_t)(t+1)*BBATCH + r)*HHID + kg];
          v = make_float4((a.x+h.x)*INV_SQRT2,(a.y+h.y)*INV_SQRT2,(a.z+h.z)*INV_SQRT2,(a.w+h.w)*INV_SQRT2);
        }
        else if (ch == 2) v = *(const float4*)&p.ctxX[((size_t)(t+1)*BBATCH + r)*AATT + (kg-512)];
        else              v = *(const float4*)&p.ohX[((size_t)t*BBATCH + r)*HHID + (kg-768)];
        *(float4*)&smem[r*260 + kq] = v;
      }
      __syncthreads();
      const float* wch = wpw + (ch << 11);
      const float* xr = &smem[row*260];
      #pragma unroll 16
      for (int i = 0; i < 64; ++i) {
        float4 xv = *(const float4*)&xr[i<<2];
        float4 wv = *(const float4*)&wch[(i<<5) + gsh];
        a0 = fmaf(xv.x, wv.x, a0);
        a1 = fmaf(xv.y, wv.y, a1);
        a2 = fmaf(xv.z, wv.z, a2);
        a3 = fmaf(xv.w, wv.w, a3);
      }
    }
    gbuf[(row<<3) + gci] = (a0 + a1) + (a2 + a3) + bsum;
    __syncthreads();
    if (tid < 128) {
      int r = tid >> 1, jq = tid & 1;
      float gi = sigm(gbuf[(r<<3) + 0 + jq]);
      float gf = sigm(gbuf[(r<<3) + 2 + jq]);
      float gz = tanhf(gbuf[(r<<3) + 4 + jq]);
      float go = sigm(gbuf[(r<<3) + 6 + jq]);
      float cp = cstate[(r<<1)+jq];
      float cn = fmaf(gf, cp, gi*gz);
      cstate[(r<<1)+jq] = cn;
      float hn = go * tanhf(cn);
      g_store(&p.ohX[((size_t)(t+1)*BBATCH + r)*HHID + ((wg<<1)+jq)], hn);  // sc1 -> LLC
    }
    gridbar(p.bars1, ++gen);
  }
}

__global__ void k_sentinel(float* o) { o[blockIdx.x*256 + threadIdx.x] = 12345.0f; }

extern "C" void kernel_launch(void* const* d_in, const int* in_sizes, int n_in,
                              void* d_out, int out_size, void* d_ws, size_t ws_size,
                              hipStream_t stream) {
  P p;
  p.tokens        = (const float*)d_in[0];
  p.num_tokens    = (const int*)d_in[2];
  p.target_frames = (const float*)d_in[3];
  p.init_W1=(const float*)d_in[4];  p.init_b1=(const float*)d_in[5];
  p.init_W2=(const float*)d_in[6];  p.init_b2=(const float*)d_in[7];
  p.pre_W1=(const float*)d_in[8];   p.pre_b1=(const float*)d_in[9];
  p.pre_W2=(const float*)d_in[10];  p.pre_b2=(const float*)d_in[11];
  p.lstm_Wih=(const float*)d_in[12]; p.lstm_Whh=(const float*)d_in[13];
  p.lstm_bih=(const float*)d_in[14]; p.lstm_bhh=(const float*)d_in[15];
  p.attn_Wq=(const float*)d_in[16]; p.attn_bq=(const float*)d_in[17];
  p.attn_conv_w=(const float*)d_in[18]; p.attn_conv_b=(const float*)d_in[19];
  p.attn_v=(const float*)d_in[20];
  p.stop_W1=(const float*)d_in[21]; p.stop_b1=(const float*)d_in[22];
  p.stop_W2=(const float*)d_in[23]; p.stop_b2=(const float*)d_in[24];
  p.olstm_Wih=(const float*)d_in[25]; p.olstm_Whh=(const float*)d_in[26];
  p.olstm_bih=(const float*)d_in[27]; p.olstm_bhh=(const float*)d_in[28];
  p.out_W1=(const float*)d_in[29];  p.out_b1=(const float*)d_in[30];
  p.out_W2=(const float*)d_in[31];  p.out_b2=(const float*)d_in[32];

  float* w = (float*)d_ws;
  p.bars0 = (int*)d_ws;          // ints [0..575]
  p.bars1 = p.bars0 + 1024;      // ints [1024..1599]
  p.pre   = w + OFF_PRE;
  p.tmp1  = w + OFF_TMP1;
  p.hX    = w + OFF_HX;
  p.ohX   = w + OFF_OHX;
  p.ctxX  = w + OFF_CTX;
  p.tokp  = w + OFF_TOKP;
  p.initf = w + OFF_INITF;
  p.begp  = w + OFF_BEGP;
  p.endp  = w + OFF_ENDP;
  p.cumg  = w + OFF_CUMG;
  p.wqt   = w + OFF_WQT;
  p.wpL   = p.tmp1;              // packed weights live in tmp1's dead window
  p.wpO   = p.tmp1 + WPO_OFF;

  p.out_frames = (float*)d_out;
  p.out_stop   = p.out_frames + OUT_STOP;
  p.out_align  = p.out_frames + OUT_ALIGN;
  p.out_ws     = p.out_frames + OUT_WS;

  (void)hipMemsetAsync(d_out, 0, (size_t)out_size * sizeof(float), stream);

  if (ws_size < (size_t)WS_TOTAL_FLOATS * sizeof(float)) {
    k_sentinel<<<128, 256, 0, stream>>>(p.out_ws);
    return;
  }

  (void)hipMemsetAsync(d_ws, 0, 8192, stream);     // barrier counters (both scans)

  k_init<<<64, 256, 0, stream>>>(p);
  k_wqt <<<512, 256, 0, stream>>>(p);
  k_tokp<<<8704, 256, 0, stream>>>(p);

  // pre = gelu(gelu(frames_in @ pre_W1^T + b1) @ pre_W2^T + b2)  (uses tmp1)
  gemm_k<128,512,1,1><<<dim3(4,256), 256, 0, stream>>>(p, p.pre_W1, p.pre_b1, p.tmp1);
  gemm_k<512,512,0,1><<<dim3(4,256), 256, 0, stream>>>(p, p.pre_W2, p.pre_b2, p.pre);

  // pack LSTM weights (tmp1 is dead from here until the out-net GEMMs)
  k_pack<<<(2*NWG*WP_PER_WG + 255)/256, 256, 0, stream>>>(p);

  k_scan<<<NWG, 512, 0, stream>>>(p);

  // stop = gelu(block @ stop_W1^T + b1) @ stop_W2^T + b2   (fused reduce)
  gemm_k<768,512,2,2><<<dim3(4,256), 256, 0, stream>>>(p, p.stop_W1, p.stop_b1, p.out_stop);

  k_oscan<<<NWG, 512, 0, stream>>>(p);

  // frames = gelu(fr2 @ out_W1^T + b1) @ out_W2^T + b2  (tmp1 reused after k_oscan)
  gemm_k<512,512,3,1><<<dim3(4,256), 256, 0, stream>>>(p, p.out_W1, p.out_b1, p.tmp1);
  gemm_k<512,128,0,0><<<dim3(1,256), 256, 0, stream>>>(p, p.out_W2, p.out_b2, p.out_frames);
}